// Round 1
// baseline (6893.902 us; speedup 1.0000x reference)
//
#include <hip/hip_runtime.h>

// ---------------------------------------------------------------------------
// Encoder_conv: emb (1x1 conv) -> 3x { multi-tap K=2 convs summed -> LSTM scan
// with per-step attention gating }.
// B=32, W=512, H=256, 4H=1024, NINP=128, K=2, NLAYERS=3.
//
// Round 6: 2 batches per WG in rec_kernel.
//  - Weights (512 KB/layer) are per-WG, not per-batch: one WG now serves a
//    batch PAIR, reusing the same pinned-VGPR weights and the same LDS weight
//    reads (lw fetched once, fdot2'd into both batches) -> amortizes barrier,
//    m_-chain, weight traffic and wave skew over 2 batches.
//  - Post-butterfly lane redundancy (s and s^2 identical) converted to work
//    split: lanes s<2 do batch A gates/stores, s>=2 batch B. Gate math per
//    batch halves vs the old kernel.
//  - Register headroom: weight split rebalanced 192/64 -> 184 VGPR + 72 LDS
//    dwords/thread (18 b128 chunks, 144 KB LDS; total 149.6 KB).
//  - 16 WGs; per-batch arithmetic order identical to round 5 (same absmax).
// ---------------------------------------------------------------------------

typedef _Float16 h2 __attribute__((ext_vector_type(2)));

static __device__ __forceinline__ float fdot2(unsigned a, unsigned b, float c) {
#if __has_builtin(__builtin_amdgcn_fdot2)
  return __builtin_amdgcn_fdot2(__builtin_bit_cast(h2, a),
                                __builtin_bit_cast(h2, b), c, false);
#else
  h2 x = __builtin_bit_cast(h2, a), y = __builtin_bit_cast(h2, b);
  return c + (float)x[0] * (float)y[0] + (float)x[1] * (float)y[1];
#endif
}

static __device__ __forceinline__ unsigned short f16b(float v) {
  _Float16 h = (_Float16)v;
  return __builtin_bit_cast(unsigned short, h);
}

static __device__ __forceinline__ float sigm(float x) {
  return 1.0f / (1.0f + __expf(-x));
}
static __device__ __forceinline__ float tanh_(float x) {
  return 1.0f - 2.0f / (1.0f + __expf(2.0f * x));
}

// Packs rec_w per layer (131072 dwords/layer) for the butterfly rec kernel.
// Thread tid: s=tid&3, u=tid>>2; rows row=(rl>>1)*256+(rl&1)*128+u (rl=0..7);
// K-pairs j in [0,32) at global pair cp = s*32+j.
// New split: VGPR part 184 dw/thread (rl<2: j 0..19; rl>=2: j 0..23),
// LDS part 72 dw/thread as 18 chunks of [512 threads][4 dw]:
//   rl<2 : qL in {5,6,7}, chunk c = rl*3 + (qL-5)        (c 0..5)
//   rl>=2: qL in {6,7},   chunk c = 6 + (rl-2)*2 + (qL-6) (c 6..17)
//   j = qL*4 + k
__global__ __launch_bounds__(256) void prep_rw(const float* __restrict__ rw,
                                               unsigned* __restrict__ rwp) {
  int idx = blockIdx.x * 256 + threadIdx.x;
  if (idx >= 3 * 131072) return;
  int l = idx / 131072, pos = idx % 131072;
  int tid, rl, j;
  if (pos < 94208) {               // VGPR region: 184 * 512
    int d = pos >> 9;
    tid = pos & 511;
    if (d < 40) {
      rl = d / 20;
      j = d % 20;
    } else {
      int e = d - 40;
      rl = 2 + e / 24;
      j = e % 24;
    }
  } else {                          // LDS region: 18 chunks * 2048
    int p = pos - 94208;
    int c = p >> 11, rem = p & 2047;
    tid = rem >> 2;
    int k = rem & 3, qL;
    if (c < 6) {
      rl = c / 3;
      qL = 5 + c % 3;
    } else {
      rl = 2 + (c - 6) / 2;
      qL = 6 + ((c - 6) & 1);
    }
    j = qL * 4 + k;
  }
  int s = tid & 3, u = tid >> 2;
  int row = (rl >> 1) * 256 + (rl & 1) * 128 + u;
  int cp = s * 32 + j;
  const float* src = rw + (l * 1024 + row) * 256 + 2 * cp;
  rwp[idx] = (unsigned)f16b(src[0]) | ((unsigned)f16b(src[1]) << 16);
}

// cwp[jj][o][k][d] = pack(f16(conv_w[jj][o][2d][k]), f16(conv_w[jj][o][2d+1][k]))
__global__ __launch_bounds__(256) void prep_cw(const float* __restrict__ cw,
                                               unsigned* __restrict__ cwp) {
  int idx = blockIdx.x * 256 + threadIdx.x;
  if (idx >= 6 * 1024 * 2 * 128) return;
  int d = idx & 127, k = (idx >> 7) & 1, o = (idx >> 8) & 1023, jj = idx >> 18;
  const float* src = cw + ((jj * 1024 + o) * 256 + 2 * d) * 2 + k;
  unsigned v = (unsigned)f16b(src[0]) | ((unsigned)f16b(src[2]) << 16);
  cwp[idx] = v;
}

// x0[b,w,h] = sum_c emb_w[h,c]*input[b,c,w] + emb_b[h]; store f16 + out tail.
__global__ __launch_bounds__(256) void emb_kernel(
    const float* __restrict__ inp, const float* __restrict__ ew,
    const float* __restrict__ eb, unsigned short* __restrict__ x0f,
    float* __restrict__ out) {
  __shared__ float xt[32][65];
  __shared__ float wt[64][33];
  int b = blockIdx.z, w0 = blockIdx.x * 64, h0 = blockIdx.y * 64;
  int tid = threadIdx.x, tx = tid & 15, ty = tid >> 4;
  float acc[4][4] = {};
  for (int c0 = 0; c0 < 128; c0 += 32) {
    __syncthreads();
#pragma unroll
    for (int i = 0; i < 8; i++) {
      int f = i * 256 + tid, c = f >> 6, wl = f & 63;
      xt[c][wl] = inp[(b * 128 + c0 + c) * 512 + w0 + wl];
    }
#pragma unroll
    for (int i = 0; i < 8; i++) {
      int f = i * 256 + tid, h = f >> 5, c = f & 31;
      wt[h][c] = ew[(h0 + h) * 128 + c0 + c];
    }
    __syncthreads();
#pragma unroll
    for (int c = 0; c < 32; c++) {
      float xv[4], wv[4];
#pragma unroll
      for (int q = 0; q < 4; q++) xv[q] = xt[c][ty * 4 + q];
#pragma unroll
      for (int p = 0; p < 4; p++) wv[p] = wt[tx * 4 + p][c];
#pragma unroll
      for (int q = 0; q < 4; q++)
#pragma unroll
        for (int p = 0; p < 4; p++) acc[q][p] += xv[q] * wv[p];
    }
  }
#pragma unroll
  for (int q = 0; q < 4; q++) {
    int w = w0 + ty * 4 + q;
#pragma unroll
    for (int p = 0; p < 4; p++) {
      int h = h0 + tx * 4 + p;
      float v = acc[q][p] + eb[h];
      x0f[(b * 512 + w) * 256 + h] = f16b(v);
      if (w >= 510) out[(b * 256 + h) * 2 + (w - 510)] = v;  // x[0] tail
    }
  }
}

// ig[b,w,o] = sum_j sum_{i,k} xpad_j[b,w-1+k,i] * cw[off+j][o,i,k] + biases
__global__ __launch_bounds__(256) void conv_kernel(
    const unsigned short* __restrict__ xf, const unsigned* __restrict__ cwp,
    const float* __restrict__ cb, const float* __restrict__ hidden,
    unsigned short* __restrict__ igf, int l, int off) {
  __shared__ __align__(16) unsigned xs[65][20];    // [pad-col][dw16], stride 20
  __shared__ __align__(16) unsigned wsm[2][16][66];// [k][dw16][o], pad 66
  int b = blockIdx.z, w0 = blockIdx.x * 64, o0 = blockIdx.y * 64;
  int tid = threadIdx.x, tx = tid & 15, ty = tid >> 4;
  float acc[4][4] = {};
  int nl = l + 1;
  for (int j = 0; j < nl; j++) {
    const unsigned* xj = (const unsigned*)(xf + j * 4194304 + b * 512 * 256);
    const unsigned* cwj = cwp + (off + j) * 262144;
    for (int c0 = 0; c0 < 256; c0 += 32) {
      int d0 = c0 >> 1;
      __syncthreads();
#pragma unroll
      for (int i = 0; i < 5; i++) {
        int f = i * 256 + tid;
        if (f < 1040) {
          int col = f >> 4, dw = f & 15;
          int w = w0 - 1 + col;
          unsigned v;
          if (w >= 0) {
            v = xj[w * 128 + d0 + dw];
          } else {  // left pad: hidden[j][b][i][1]
            const float* hp = hidden + ((j * 32 + b) * 256 + 2 * (d0 + dw)) * 2 + 1;
            v = (unsigned)f16b(hp[0]) | ((unsigned)f16b(hp[2]) << 16);
          }
          xs[col][dw] = v;
        }
      }
#pragma unroll
      for (int i = 0; i < 8; i++) {
        int f = i * 256 + tid;
        int oo = f >> 5, k = (f >> 4) & 1, dw = f & 15;
        wsm[k][dw][oo] = cwj[(o0 + oo) * 256 + k * 128 + d0 + dw];
      }
      __syncthreads();
#pragma unroll
      for (int g = 0; g < 4; g++) {
        uint4 xv[5];
#pragma unroll
        for (int q = 0; q < 5; q++)
          xv[q] = *(const uint4*)&xs[ty * 4 + q][g * 4];
#pragma unroll
        for (int p = 0; p < 4; p++) {
          unsigned wv0[4], wv1[4];
#pragma unroll
          for (int r = 0; r < 4; r++) {
            wv0[r] = wsm[0][g * 4 + r][tx * 4 + p];
            wv1[r] = wsm[1][g * 4 + r][tx * 4 + p];
          }
#pragma unroll
          for (int q = 0; q < 4; q++) {
            float a = acc[q][p];
            a = fdot2(wv0[0], xv[q].x, a);
            a = fdot2(wv0[1], xv[q].y, a);
            a = fdot2(wv0[2], xv[q].z, a);
            a = fdot2(wv0[3], xv[q].w, a);
            a = fdot2(wv1[0], xv[q + 1].x, a);
            a = fdot2(wv1[1], xv[q + 1].y, a);
            a = fdot2(wv1[2], xv[q + 1].z, a);
            a = fdot2(wv1[3], xv[q + 1].w, a);
            acc[q][p] = a;
          }
        }
      }
    }
  }
#pragma unroll
  for (int p = 0; p < 4; p++) {
    int o = o0 + tx * 4 + p;
    float bias = 0.f;
    for (int j = 0; j < nl; j++) bias += cb[(off + j) * 1024 + o];
#pragma unroll
    for (int q = 0; q < 4; q++) {
      int w = w0 + ty * 4 + q;
      igf[(b * 512 + w) * 1024 + o] = f16b(acc[q][p] + bias);
    }
  }
}

// One WG per batch PAIR; 512 threads; lane (s=tid&3, u=tid>>2) computes 8
// partial row-dots over 1/4 of hx for BOTH batches (shared weights),
// butterfly-reduced in-wave. Gate math split by s: s<2 -> batch A, s>=2 -> B.
// 1 barrier/step.
__global__ __launch_bounds__(512)
__attribute__((amdgpu_waves_per_eu(2, 2)))
void rec_kernel(const _Float16* __restrict__ igf, const unsigned* __restrict__ rwp_l,
                const float* __restrict__ rb, const float* __restrict__ aw,
                const float* __restrict__ hidden, const float* __restrict__ context,
                int l, unsigned short* __restrict__ xnext, float* __restrict__ out) {
  __shared__ __align__(16) uint4 w_lds4[18 * 512];            // 144 KB
  __shared__ __align__(16) unsigned short hx_buf[2][2][256];  // [batch][dbuf][unit]
  __shared__ float red[2][2][8];                              // [batch][dbuf][wid]
  int bp = blockIdx.x, tid = threadIdx.x;
  int s = tid & 3, u = tid >> 2, lane = tid & 63, wid = tid >> 6;
  int hh = s & 1, bs = s >> 1;
  int u2 = u + 128 * hh;      // this lane's unit
  int b = bp * 2 + bs;        // this lane's batch (for gate/store work)

  // 184 weight dwords -> pinned VGPRs (shared across both batches)
  unsigned wv[184];
#pragma unroll
  for (int d = 0; d < 184; d++) wv[d] = rwp_l[d * 512 + tid];
#pragma unroll
  for (int d = 0; d < 184; d++) asm volatile("" : "+v"(wv[d]));

  // 72 weight dwords -> LDS (18 conflict-free b128 chunks)
  {
    const uint4* g16 = (const uint4*)(rwp_l + 94208);
#pragma unroll
    for (int c = 0; c < 18; c++) w_lds4[c * 512 + tid] = g16[c * 512 + tid];
  }

  float rb0 = rb[u2], rb1 = rb[256 + u2], rb2 = rb[512 + u2], rb3 = rb[768 + u2];
  float awj = aw[u2];
  float cx = context[((l * 32 + b) * 256 + u2) * 2 + 1];
  {
    int bb = tid >> 8, hu = tid & 255;
    hx_buf[bb][1][hu] =
        f16b(hidden[(((l + 1) * 32 + bp * 2 + bb) * 256 + hu) * 2 + 1]);
  }
  float h_prev = 0.f;
  __syncthreads();

  const _Float16* igb = igf + (b * 512) * 1024 + u2;

  for (int t = 0; t < 512; t++) {
    int cur = t & 1, prv = cur ^ 1;
    // ig prefetch for own batch (consumed after butterfly, ~1000 cyc later)
    const _Float16* ip = igb + t * 1024;
    float ig0 = (float)ip[0], ig1 = (float)ip[256];
    float ig2 = (float)ip[512], ig3 = (float)ip[768];
    // m = a_(t-1) for own batch: deferred gating scalar (dot(w,a*h)=a*dot(w,h))
    float m_ = 1.0f;
    if (t) {
      const float* rp = red[bs][prv];
      m_ = sigm(((rp[0] + rp[1]) + (rp[2] + rp[3])) +
                ((rp[4] + rp[5]) + (rp[6] + rp[7])));
    }

    float aA[8] = {}, aB[8] = {};
    const uint4* hqA = ((const uint4*)hx_buf[0][prv]) + 8 * s;
    const uint4* hqB = ((const uint4*)hx_buf[1][prv]) + 8 * s;
#pragma unroll
    for (int q = 0; q < 5; q++) {
      uint4 hA = hqA[q], hB = hqB[q];
#pragma unroll
      for (int rl = 0; rl < 8; rl++) {
        int base = (rl < 2) ? (rl * 20 + q * 4) : (40 + (rl - 2) * 24 + q * 4);
        aA[rl] = fdot2(wv[base + 0], hA.x, aA[rl]);
        aA[rl] = fdot2(wv[base + 1], hA.y, aA[rl]);
        aA[rl] = fdot2(wv[base + 2], hA.z, aA[rl]);
        aA[rl] = fdot2(wv[base + 3], hA.w, aA[rl]);
        aB[rl] = fdot2(wv[base + 0], hB.x, aB[rl]);
        aB[rl] = fdot2(wv[base + 1], hB.y, aB[rl]);
        aB[rl] = fdot2(wv[base + 2], hB.z, aB[rl]);
        aB[rl] = fdot2(wv[base + 3], hB.w, aB[rl]);
      }
    }
    {  // q = 5: rl 0,1 from LDS chunk rl*3; rl 2..7 from VGPR
      uint4 hA = hqA[5], hB = hqB[5];
#pragma unroll
      for (int rl = 0; rl < 2; rl++) {
        uint4 lw = w_lds4[(rl * 3) * 512 + tid];
        aA[rl] = fdot2(lw.x, hA.x, aA[rl]);
        aA[rl] = fdot2(lw.y, hA.y, aA[rl]);
        aA[rl] = fdot2(lw.z, hA.z, aA[rl]);
        aA[rl] = fdot2(lw.w, hA.w, aA[rl]);
        aB[rl] = fdot2(lw.x, hB.x, aB[rl]);
        aB[rl] = fdot2(lw.y, hB.y, aB[rl]);
        aB[rl] = fdot2(lw.z, hB.z, aB[rl]);
        aB[rl] = fdot2(lw.w, hB.w, aB[rl]);
      }
#pragma unroll
      for (int rl = 2; rl < 8; rl++) {
        int base = 40 + (rl - 2) * 24 + 20;
        aA[rl] = fdot2(wv[base + 0], hA.x, aA[rl]);
        aA[rl] = fdot2(wv[base + 1], hA.y, aA[rl]);
        aA[rl] = fdot2(wv[base + 2], hA.z, aA[rl]);
        aA[rl] = fdot2(wv[base + 3], hA.w, aA[rl]);
        aB[rl] = fdot2(wv[base + 0], hB.x, aB[rl]);
        aB[rl] = fdot2(wv[base + 1], hB.y, aB[rl]);
        aB[rl] = fdot2(wv[base + 2], hB.z, aB[rl]);
        aB[rl] = fdot2(wv[base + 3], hB.w, aB[rl]);
      }
    }
#pragma unroll
    for (int qq = 6; qq < 8; qq++) {  // all rl from LDS
      uint4 hA = hqA[qq], hB = hqB[qq];
#pragma unroll
      for (int rl = 0; rl < 8; rl++) {
        int c = (rl < 2) ? (rl * 3 + (qq - 5)) : (6 + (rl - 2) * 2 + (qq - 6));
        uint4 lw = w_lds4[c * 512 + tid];
        aA[rl] = fdot2(lw.x, hA.x, aA[rl]);
        aA[rl] = fdot2(lw.y, hA.y, aA[rl]);
        aA[rl] = fdot2(lw.z, hA.z, aA[rl]);
        aA[rl] = fdot2(lw.w, hA.w, aA[rl]);
        aB[rl] = fdot2(lw.x, hB.x, aB[rl]);
        aB[rl] = fdot2(lw.y, hB.y, aB[rl]);
        aB[rl] = fdot2(lw.z, hB.z, aB[rl]);
        aB[rl] = fdot2(lw.w, hB.w, aB[rl]);
      }
    }
    // butterfly over s (xor 1, then 2): all 4 lanes end with identical sums
#pragma unroll
    for (int rl = 0; rl < 8; rl++) {
      aA[rl] += __shfl_xor(aA[rl], 1);
      aB[rl] += __shfl_xor(aB[rl], 1);
    }
#pragma unroll
    for (int rl = 0; rl < 8; rl++) {
      aA[rl] += __shfl_xor(aA[rl], 2);
      aB[rl] += __shfl_xor(aB[rl], 2);
    }

    // this lane's 4 gates for its OWN batch (rows g*256 + u2 <-> acc[g*2+hh])
    float d0 = bs ? aB[0] : aA[0], d1 = bs ? aB[1] : aA[1];
    float d2 = bs ? aB[2] : aA[2], d3 = bs ? aB[3] : aA[3];
    float d4 = bs ? aB[4] : aA[4], d5 = bs ? aB[5] : aA[5];
    float d6 = bs ? aB[6] : aA[6], d7 = bs ? aB[7] : aA[7];
    float di = hh ? d1 : d0;
    float df = hh ? d3 : d2;
    float dc = hh ? d5 : d4;
    float do_ = hh ? d7 : d6;
    float g_i = ig0 + rb0 + m_ * di;
    float g_f = ig1 + rb1 + m_ * df;
    float g_c = ig2 + rb2 + m_ * dc;
    float g_o = ig3 + rb3 + m_ * do_;
    cx = sigm(g_f) * cx + sigm(g_i) * tanh_(g_c);
    float h_raw = sigm(g_o) * tanh_(cx);

    // attention partial: every lane contributes its own (batch, u2) once.
    // Reduce over u (xor 4,8,16,32) then hh (xor 1); NEVER xor 2 (batch axis).
    float part = h_raw * awj;
    part += __shfl_xor(part, 4);
    part += __shfl_xor(part, 8);
    part += __shfl_xor(part, 16);
    part += __shfl_xor(part, 32);
    part += __shfl_xor(part, 1);
    if (lane == 0) red[0][cur][wid] = part;
    if (lane == 2) red[1][cur][wid] = part;

    hx_buf[bs][cur][u2] = f16b(h_raw);  // store RAW h; gating deferred
    if (t) {
      float hg = h_prev * m_;  // gated h of step t-1 (own batch)
      xnext[(b * 512 + (t - 1)) * 256 + u2] = f16b(hg);
      if (t == 511)
        out[(((l + 1) * 32 + b) * 256 + u2) * 2 + 0] = hg;  // x tail w=510
    }
    if (t >= 510)
      out[65536 + ((l * 32 + b) * 256 + u2) * 2 + (t - 510)] = cx;  // nc tail
    if (t && u == 0 && hh == 0)  // tid 0 -> batch A, tid 2 -> batch B
      out[114688 + (l * 32 + b) * 511 + (t - 1)] = m_;  // attn
    h_prev = h_raw;
    __syncthreads();
  }
  // flush last step (ungated), each lane its own batch/unit
  xnext[(b * 512 + 511) * 256 + u2] = f16b(h_prev);
  out[(((l + 1) * 32 + b) * 256 + u2) * 2 + 1] = h_prev;  // x tail w=511
}

extern "C" void kernel_launch(void* const* d_in, const int* in_sizes, int n_in,
                              void* d_out, int out_size, void* d_ws,
                              size_t ws_size, hipStream_t stream) {
  const float* input  = (const float*)d_in[0];
  const float* hidden = (const float*)d_in[1];
  const float* context= (const float*)d_in[2];
  const float* emb_w  = (const float*)d_in[3];
  const float* emb_b  = (const float*)d_in[4];
  const float* conv_w = (const float*)d_in[5];
  const float* conv_b = (const float*)d_in[6];
  const float* rec_w  = (const float*)d_in[7];
  const float* rec_b  = (const float*)d_in[8];
  const float* attn_w = (const float*)d_in[9];
  float* out = (float*)d_out;

  char* ws = (char*)d_ws;
  unsigned short* xf16 = (unsigned short*)ws;                    // 4 x 4,194,304 f16 = 32 MB
  _Float16* igf = (_Float16*)(ws + 33554432);                    // 16,777,216 f16 = 32 MB
  unsigned* rwp = (unsigned*)(ws + 67108864);                    // 1.5 MB
  unsigned* cwp = (unsigned*)(ws + 68681728);                    // 6 MB

  hipLaunchKernelGGL(prep_rw, dim3(1536), dim3(256), 0, stream, rec_w, rwp);
  hipLaunchKernelGGL(prep_cw, dim3(6144), dim3(256), 0, stream, conv_w, cwp);
  hipLaunchKernelGGL(emb_kernel, dim3(8, 4, 32), dim3(256), 0, stream,
                     input, emb_w, emb_b, xf16, out);
  int off = 0;
  for (int l = 0; l < 3; l++) {
    hipLaunchKernelGGL(conv_kernel, dim3(8, 16, 32), dim3(256), 0, stream,
                       xf16, cwp, conv_b, hidden, (unsigned short*)igf, l, off);
    hipLaunchKernelGGL(rec_kernel, dim3(16), dim3(512), 0, stream,
                       igf, rwp + l * 131072, rec_b + l * 1024,
                       attn_w + l * 256, hidden, context, l,
                       xf16 + (l + 1) * 4194304, out);
    off += l + 1;
  }
}

// Round 2
// 5784.415 us; speedup vs baseline: 1.1918x; 1.1918x over previous
//
#include <hip/hip_runtime.h>

// ---------------------------------------------------------------------------
// Encoder_conv: emb (1x1 conv) -> 3x { multi-tap K=2 convs summed -> LSTM scan
// with per-step attention gating }.
// B=32, W=512, H=256, 4H=1024, NINP=128, K=2, NLAYERS=3.
//
// Round 7: revert round-6 (batch-pairing doubled the sequential per-step
// critical path; scan wall time = 512 * single-WG step latency). Back to
// 1 batch/WG (32 WGs), then cut DS-pipe work per step:
//  - main butterfly xor1/xor2 via DPP quad_perm adds (VALU) instead of
//    16 ds_bpermute/thread/step. Bit-identical summation order.
//  - hx_buf quarter stride 72 elems (144B): the 4 s-quarter read addresses
//    previously sat 128B apart = same bank quad -> 4-way conflict on every
//    h read (matches the 4.46M SQ_LDS_BANK_CONFLICT). Now one bank-quad
//    apart each -> conflict-free broadcast.
//  - red[] consumed as 2x float4 (2 DS ops, was 8 scalar reads).
//  - attn reduce: DPP xor1 + mask + 4 shfls (was 6 shfls).
// Weights unchanged: 192 dw/thread pinned VGPRs + 64 dw/thread LDS (128 KB).
// ---------------------------------------------------------------------------

typedef _Float16 h2 __attribute__((ext_vector_type(2)));

static __device__ __forceinline__ float fdot2(unsigned a, unsigned b, float c) {
#if __has_builtin(__builtin_amdgcn_fdot2)
  return __builtin_amdgcn_fdot2(__builtin_bit_cast(h2, a),
                                __builtin_bit_cast(h2, b), c, false);
#else
  h2 x = __builtin_bit_cast(h2, a), y = __builtin_bit_cast(h2, b);
  return c + (float)x[0] * (float)y[0] + (float)x[1] * (float)y[1];
#endif
}

static __device__ __forceinline__ unsigned short f16b(float v) {
  _Float16 h = (_Float16)v;
  return __builtin_bit_cast(unsigned short, h);
}

static __device__ __forceinline__ float sigm(float x) {
  return 1.0f / (1.0f + __expf(-x));
}
static __device__ __forceinline__ float tanh_(float x) {
  return 1.0f - 2.0f / (1.0f + __expf(2.0f * x));
}

// x + (x from lane^delta) within each quad, via DPP quad_perm. CTRL:
// xor1 = quad_perm(1,0,3,2) = 0xB1 ; xor2 = quad_perm(2,3,0,1) = 0x4E.
template <int CTRL>
static __device__ __forceinline__ float dpp_xadd(float x) {
  int y = __builtin_amdgcn_mov_dpp(__builtin_bit_cast(int, x), CTRL, 0xF, 0xF,
                                   true);
  return x + __builtin_bit_cast(float, y);
}

// Packs rec_w per layer (131072 dwords/layer) for the butterfly rec kernel.
// Thread tid: s=tid&3, u=tid>>2; rows row=(rl>>1)*256+(rl&1)*128+u (rl=0..7);
// K-pairs j in [0,32) at global pair cp = s*32+j:
//   j<24      -> VGPR: off = (rl*24+j)*512 + tid
//   j=24..31  -> LDS : c = rl*2+((j-24)>>2), k=(j-24)&3
//                      off = 98304 + c*2048 + tid*4 + k
__global__ __launch_bounds__(256) void prep_rw(const float* __restrict__ rw,
                                               unsigned* __restrict__ rwp) {
  int idx = blockIdx.x * 256 + threadIdx.x;
  if (idx >= 3 * 131072) return;
  int l = idx / 131072, pos = idx % 131072;
  int tid, rl, j;
  if (pos < 98304) {
    int d = pos >> 9;
    tid = pos & 511;
    rl = d / 24;
    j = d % 24;
  } else {
    int p = pos - 98304;
    int c = p >> 11, rem = p & 2047;
    tid = rem >> 2;
    int k = rem & 3;
    rl = c >> 1;
    j = 24 + (c & 1) * 4 + k;
  }
  int s = tid & 3, u = tid >> 2;
  int row = (rl >> 1) * 256 + (rl & 1) * 128 + u;
  int cp = s * 32 + j;
  const float* src = rw + (l * 1024 + row) * 256 + 2 * cp;
  rwp[idx] = (unsigned)f16b(src[0]) | ((unsigned)f16b(src[1]) << 16);
}

// cwp[jj][o][k][d] = pack(f16(conv_w[jj][o][2d][k]), f16(conv_w[jj][o][2d+1][k]))
__global__ __launch_bounds__(256) void prep_cw(const float* __restrict__ cw,
                                               unsigned* __restrict__ cwp) {
  int idx = blockIdx.x * 256 + threadIdx.x;
  if (idx >= 6 * 1024 * 2 * 128) return;
  int d = idx & 127, k = (idx >> 7) & 1, o = (idx >> 8) & 1023, jj = idx >> 18;
  const float* src = cw + ((jj * 1024 + o) * 256 + 2 * d) * 2 + k;
  unsigned v = (unsigned)f16b(src[0]) | ((unsigned)f16b(src[2]) << 16);
  cwp[idx] = v;
}

// x0[b,w,h] = sum_c emb_w[h,c]*input[b,c,w] + emb_b[h]; store f16 + out tail.
__global__ __launch_bounds__(256) void emb_kernel(
    const float* __restrict__ inp, const float* __restrict__ ew,
    const float* __restrict__ eb, unsigned short* __restrict__ x0f,
    float* __restrict__ out) {
  __shared__ float xt[32][65];
  __shared__ float wt[64][33];
  int b = blockIdx.z, w0 = blockIdx.x * 64, h0 = blockIdx.y * 64;
  int tid = threadIdx.x, tx = tid & 15, ty = tid >> 4;
  float acc[4][4] = {};
  for (int c0 = 0; c0 < 128; c0 += 32) {
    __syncthreads();
#pragma unroll
    for (int i = 0; i < 8; i++) {
      int f = i * 256 + tid, c = f >> 6, wl = f & 63;
      xt[c][wl] = inp[(b * 128 + c0 + c) * 512 + w0 + wl];
    }
#pragma unroll
    for (int i = 0; i < 8; i++) {
      int f = i * 256 + tid, h = f >> 5, c = f & 31;
      wt[h][c] = ew[(h0 + h) * 128 + c0 + c];
    }
    __syncthreads();
#pragma unroll
    for (int c = 0; c < 32; c++) {
      float xv[4], wv[4];
#pragma unroll
      for (int q = 0; q < 4; q++) xv[q] = xt[c][ty * 4 + q];
#pragma unroll
      for (int p = 0; p < 4; p++) wv[p] = wt[tx * 4 + p][c];
#pragma unroll
      for (int q = 0; q < 4; q++)
#pragma unroll
        for (int p = 0; p < 4; p++) acc[q][p] += xv[q] * wv[p];
    }
  }
#pragma unroll
  for (int q = 0; q < 4; q++) {
    int w = w0 + ty * 4 + q;
#pragma unroll
    for (int p = 0; p < 4; p++) {
      int h = h0 + tx * 4 + p;
      float v = acc[q][p] + eb[h];
      x0f[(b * 512 + w) * 256 + h] = f16b(v);
      if (w >= 510) out[(b * 256 + h) * 2 + (w - 510)] = v;  // x[0] tail
    }
  }
}

// ig[b,w,o] = sum_j sum_{i,k} xpad_j[b,w-1+k,i] * cw[off+j][o,i,k] + biases
__global__ __launch_bounds__(256) void conv_kernel(
    const unsigned short* __restrict__ xf, const unsigned* __restrict__ cwp,
    const float* __restrict__ cb, const float* __restrict__ hidden,
    unsigned short* __restrict__ igf, int l, int off) {
  __shared__ __align__(16) unsigned xs[65][20];    // [pad-col][dw16], stride 20
  __shared__ __align__(16) unsigned wsm[2][16][66];// [k][dw16][o], pad 66
  int b = blockIdx.z, w0 = blockIdx.x * 64, o0 = blockIdx.y * 64;
  int tid = threadIdx.x, tx = tid & 15, ty = tid >> 4;
  float acc[4][4] = {};
  int nl = l + 1;
  for (int j = 0; j < nl; j++) {
    const unsigned* xj = (const unsigned*)(xf + j * 4194304 + b * 512 * 256);
    const unsigned* cwj = cwp + (off + j) * 262144;
    for (int c0 = 0; c0 < 256; c0 += 32) {
      int d0 = c0 >> 1;
      __syncthreads();
#pragma unroll
      for (int i = 0; i < 5; i++) {
        int f = i * 256 + tid;
        if (f < 1040) {
          int col = f >> 4, dw = f & 15;
          int w = w0 - 1 + col;
          unsigned v;
          if (w >= 0) {
            v = xj[w * 128 + d0 + dw];
          } else {  // left pad: hidden[j][b][i][1]
            const float* hp = hidden + ((j * 32 + b) * 256 + 2 * (d0 + dw)) * 2 + 1;
            v = (unsigned)f16b(hp[0]) | ((unsigned)f16b(hp[2]) << 16);
          }
          xs[col][dw] = v;
        }
      }
#pragma unroll
      for (int i = 0; i < 8; i++) {
        int f = i * 256 + tid;
        int oo = f >> 5, k = (f >> 4) & 1, dw = f & 15;
        wsm[k][dw][oo] = cwj[(o0 + oo) * 256 + k * 128 + d0 + dw];
      }
      __syncthreads();
#pragma unroll
      for (int g = 0; g < 4; g++) {
        uint4 xv[5];
#pragma unroll
        for (int q = 0; q < 5; q++)
          xv[q] = *(const uint4*)&xs[ty * 4 + q][g * 4];
#pragma unroll
        for (int p = 0; p < 4; p++) {
          unsigned wv0[4], wv1[4];
#pragma unroll
          for (int r = 0; r < 4; r++) {
            wv0[r] = wsm[0][g * 4 + r][tx * 4 + p];
            wv1[r] = wsm[1][g * 4 + r][tx * 4 + p];
          }
#pragma unroll
          for (int q = 0; q < 4; q++) {
            float a = acc[q][p];
            a = fdot2(wv0[0], xv[q].x, a);
            a = fdot2(wv0[1], xv[q].y, a);
            a = fdot2(wv0[2], xv[q].z, a);
            a = fdot2(wv0[3], xv[q].w, a);
            a = fdot2(wv1[0], xv[q + 1].x, a);
            a = fdot2(wv1[1], xv[q + 1].y, a);
            a = fdot2(wv1[2], xv[q + 1].z, a);
            a = fdot2(wv1[3], xv[q + 1].w, a);
            acc[q][p] = a;
          }
        }
      }
    }
  }
#pragma unroll
  for (int p = 0; p < 4; p++) {
    int o = o0 + tx * 4 + p;
    float bias = 0.f;
    for (int j = 0; j < nl; j++) bias += cb[(off + j) * 1024 + o];
#pragma unroll
    for (int q = 0; q < 4; q++) {
      int w = w0 + ty * 4 + q;
      igf[(b * 512 + w) * 1024 + o] = f16b(acc[q][p] + bias);
    }
  }
}

// One WG per batch; 512 threads; lane (s=tid&3, u=tid>>2) computes 8 partial
// row-dots over 1/4 of hx, butterfly-reduced via DPP. 1 barrier/step.
__global__ __launch_bounds__(512)
__attribute__((amdgpu_waves_per_eu(2, 2)))
void rec_kernel(const _Float16* __restrict__ igf, const unsigned* __restrict__ rwp_l,
                const float* __restrict__ rb, const float* __restrict__ aw,
                const float* __restrict__ hidden, const float* __restrict__ context,
                int l, unsigned short* __restrict__ xnext, float* __restrict__ out) {
  __shared__ __align__(16) uint4 w_lds4[16 * 512];          // 128 KB
  // quarter s at elem offset s*72 (144B) -> each quarter on its own bank quad
  __shared__ __align__(16) unsigned short hx_buf[2][288];
  __shared__ __align__(16) float red[2][8];                 // attn partials
  int b = blockIdx.x, tid = threadIdx.x;
  int s = tid & 3, u = tid >> 2, lane = tid & 63, wid = tid >> 6;
  int hh = s & 1;
  int u2 = u + 128 * hh;  // this lane's unit
  int hxi = (u2 >> 6) * 72 + (u2 & 63);  // swizzled store index for u2

  // 192 weight dwords -> pinned VGPRs
  unsigned wv[192];
#pragma unroll
  for (int d = 0; d < 192; d++) wv[d] = rwp_l[d * 512 + tid];
#pragma unroll
  for (int d = 0; d < 192; d++) asm volatile("" : "+v"(wv[d]));

  // 64 weight dwords -> LDS (conflict-free b128)
  {
    const uint4* g16 = (const uint4*)(rwp_l + 98304);
#pragma unroll
    for (int c = 0; c < 16; c++) w_lds4[c * 512 + tid] = g16[c * 512 + tid];
  }

  float rb0 = rb[u2], rb1 = rb[256 + u2], rb2 = rb[512 + u2], rb3 = rb[768 + u2];
  float awj = aw[u2];
  float cx = context[((l * 32 + b) * 256 + u2) * 2 + 1];
  if (tid < 256)
    hx_buf[1][(tid >> 6) * 72 + (tid & 63)] =
        f16b(hidden[(((l + 1) * 32 + b) * 256 + tid) * 2 + 1]);
  float h_prev = 0.f;
  __syncthreads();

  const _Float16* igb = igf + (b * 512) * 1024 + u2;

  for (int t = 0; t < 512; t++) {
    int cur = t & 1, prv = cur ^ 1;
    // ig prefetch (consumed after butterfly, ~1000 cyc later)
    const _Float16* ip = igb + t * 1024;
    float ig0 = (float)ip[0], ig1 = (float)ip[256];
    float ig2 = (float)ip[512], ig3 = (float)ip[768];
    // m = a_(t-1): deferred gating scalar (dot(w, a*h) = a*dot(w,h))
    float m_ = 1.0f;
    if (t) {
      const float4* rp = (const float4*)red[prv];
      float4 ra = rp[0], rb4 = rp[1];
      m_ = sigm(((ra.x + ra.y) + (ra.z + ra.w)) +
                ((rb4.x + rb4.y) + (rb4.z + rb4.w)));
    }

    float acc[8] = {};
    const uint4* hq = (const uint4*)(&hx_buf[prv][s * 72]);
#pragma unroll
    for (int q = 0; q < 6; q++) {
      uint4 h = hq[q];
#pragma unroll
      for (int rl = 0; rl < 8; rl++) {
        acc[rl] = fdot2(wv[rl * 24 + q * 4 + 0], h.x, acc[rl]);
        acc[rl] = fdot2(wv[rl * 24 + q * 4 + 1], h.y, acc[rl]);
        acc[rl] = fdot2(wv[rl * 24 + q * 4 + 2], h.z, acc[rl]);
        acc[rl] = fdot2(wv[rl * 24 + q * 4 + 3], h.w, acc[rl]);
      }
    }
#pragma unroll
    for (int q = 6; q < 8; q++) {
      uint4 h = hq[q];
#pragma unroll
      for (int rl = 0; rl < 8; rl++) {
        uint4 lw = w_lds4[(rl * 2 + (q - 6)) * 512 + tid];
        acc[rl] = fdot2(lw.x, h.x, acc[rl]);
        acc[rl] = fdot2(lw.y, h.y, acc[rl]);
        acc[rl] = fdot2(lw.z, h.z, acc[rl]);
        acc[rl] = fdot2(lw.w, h.w, acc[rl]);
      }
    }
    // butterfly over s (xor 1, then 2) via DPP quad_perm: all 4 lanes end
    // with identical sums (IEEE add commutative -> bit-identical copies)
#pragma unroll
    for (int rl = 0; rl < 8; rl++) acc[rl] = dpp_xadd<0xB1>(acc[rl]);
#pragma unroll
    for (int rl = 0; rl < 8; rl++) acc[rl] = dpp_xadd<0x4E>(acc[rl]);

    // this lane's 4 gates (rows g*256 + u2 <-> acc[g*2+hh])
    float di = hh ? acc[1] : acc[0];
    float df = hh ? acc[3] : acc[2];
    float dc = hh ? acc[5] : acc[4];
    float do_ = hh ? acc[7] : acc[6];
    float g_i = ig0 + rb0 + m_ * di;
    float g_f = ig1 + rb1 + m_ * df;
    float g_c = ig2 + rb2 + m_ * dc;
    float g_o = ig3 + rb3 + m_ * do_;
    cx = sigm(g_f) * cx + sigm(g_i) * tanh_(g_c);
    float h_raw = sigm(g_o) * tanh_(cx);

    // attention partial: s0 holds unit u, s1 holds u+128 (distinct!);
    // DPP xor1 pair-sums them, keep only s==0 copy, then reduce over u.
    float part = (s < 2) ? h_raw * awj : 0.f;
    part = dpp_xadd<0xB1>(part);
    if (s) part = 0.f;
    part += __shfl_xor(part, 4);
    part += __shfl_xor(part, 8);
    part += __shfl_xor(part, 16);
    part += __shfl_xor(part, 32);
    if (lane == 0) red[cur][wid] = part;

    if (s < 2) {
      hx_buf[cur][hxi] = f16b(h_raw);  // store RAW h; gating deferred
      if (t) {
        float hg = h_prev * m_;  // gated h of step t-1
        xnext[(b * 512 + (t - 1)) * 256 + u2] = f16b(hg);
        if (t == 511)
          out[(((l + 1) * 32 + b) * 256 + u2) * 2 + 0] = hg;  // x tail w=510
      }
      if (t >= 510)
        out[65536 + ((l * 32 + b) * 256 + u2) * 2 + (t - 510)] = cx;  // nc tail
    }
    if (tid == 0 && t) out[114688 + (l * 32 + b) * 511 + (t - 1)] = m_;  // attn
    h_prev = h_raw;
    __syncthreads();
  }
  // flush last step (ungated)
  if (s < 2) {
    xnext[(b * 512 + 511) * 256 + u2] = f16b(h_prev);
    out[(((l + 1) * 32 + b) * 256 + u2) * 2 + 1] = h_prev;  // x tail w=511
  }
}

extern "C" void kernel_launch(void* const* d_in, const int* in_sizes, int n_in,
                              void* d_out, int out_size, void* d_ws,
                              size_t ws_size, hipStream_t stream) {
  const float* input  = (const float*)d_in[0];
  const float* hidden = (const float*)d_in[1];
  const float* context= (const float*)d_in[2];
  const float* emb_w  = (const float*)d_in[3];
  const float* emb_b  = (const float*)d_in[4];
  const float* conv_w = (const float*)d_in[5];
  const float* conv_b = (const float*)d_in[6];
  const float* rec_w  = (const float*)d_in[7];
  const float* rec_b  = (const float*)d_in[8];
  const float* attn_w = (const float*)d_in[9];
  float* out = (float*)d_out;

  char* ws = (char*)d_ws;
  unsigned short* xf16 = (unsigned short*)ws;                    // 4 x 4,194,304 f16 = 32 MB
  _Float16* igf = (_Float16*)(ws + 33554432);                    // 16,777,216 f16 = 32 MB
  unsigned* rwp = (unsigned*)(ws + 67108864);                    // 1.5 MB
  unsigned* cwp = (unsigned*)(ws + 68681728);                    // 6 MB

  hipLaunchKernelGGL(prep_rw, dim3(1536), dim3(256), 0, stream, rec_w, rwp);
  hipLaunchKernelGGL(prep_cw, dim3(6144), dim3(256), 0, stream, conv_w, cwp);
  hipLaunchKernelGGL(emb_kernel, dim3(8, 4, 32), dim3(256), 0, stream,
                     input, emb_w, emb_b, xf16, out);
  int off = 0;
  for (int l = 0; l < 3; l++) {
    hipLaunchKernelGGL(conv_kernel, dim3(8, 16, 32), dim3(256), 0, stream,
                       xf16, cwp, conv_b, hidden, (unsigned short*)igf, l, off);
    hipLaunchKernelGGL(rec_kernel, dim3(32), dim3(512), 0, stream,
                       igf, rwp + l * 131072, rec_b + l * 1024,
                       attn_w + l * 256, hidden, context, l,
                       xf16 + (l + 1) * 4194304, out);
    off += l + 1;
  }
}